// Round 9
// baseline (682.268 us; speedup 1.0000x reference)
//
#include <hip/hip_runtime.h>
#include <stdint.h>
#include <float.h>
#include <limits.h>

// ---------------------------------------------------------------------------
// Round 9 = round 8 kernel UNCHANGED + a pure-read probe dispatch to measure
// the chip's achievable streaming-read bandwidth with an ideal access pattern
// (grid-stride float4 sweep, 32 waves/CU, 2 passes over emb = 1.65 GB).
// Purpose: decide whether the GEMM's 2.6 TB/s is a structure problem or the
// read roofline. GEMM/prep/sampler are byte-identical to round 8 so the
// probe's duration can also be inferred by subtraction from r8's total.
// ---------------------------------------------------------------------------

typedef __bf16 bf16x8 __attribute__((ext_vector_type(8)));
typedef float  f32x4  __attribute__((ext_vector_type(4)));

__device__ __forceinline__ void split8v(const float* f, bf16x8& hi, bf16x8& lo) {
#pragma unroll
    for (int e = 0; e < 8; ++e) {
        const __bf16 h = (__bf16)f[e];
        hi[e] = h;
        lo[e] = (__bf16)(f[e] - (float)h);
    }
}
__device__ __forceinline__ void split8(const float* f, uint4& hi, uint4& lo) {
    bf16x8 vh, vl;
    split8v(f, vh, vl);
    hi = __builtin_bit_cast(uint4, vh);
    lo = __builtin_bit_cast(uint4, vl);
}

// ---------------------------------------------------------------------------
// read probe: ideal-pattern streaming read of src (n4 float4s), 2 passes.
// ---------------------------------------------------------------------------
__global__ __launch_bounds__(256) void read_probe(
    const float4* __restrict__ src, float* __restrict__ dst, long n4)
{
    const long stride = (long)gridDim.x * 256;
    const long g0 = (long)blockIdx.x * 256 + threadIdx.x;
    float acc = 0.f;
#pragma unroll 1
    for (int pass = 0; pass < 2; ++pass) {
        for (long i = g0; i < n4; i += stride * 4) {
            const long i1 = i + stride, i2 = i + 2 * stride, i3 = i + 3 * stride;
            float4 a = src[i];
            float4 b = (i1 < n4) ? src[i1] : make_float4(0.f, 0.f, 0.f, 0.f);
            float4 c = (i2 < n4) ? src[i2] : make_float4(0.f, 0.f, 0.f, 0.f);
            float4 d = (i3 < n4) ? src[i3] : make_float4(0.f, 0.f, 0.f, 0.f);
            acc += a.x + a.y + a.z + a.w + b.x + b.y + b.z + b.w
                 + c.x + c.y + c.z + c.w + d.x + d.y + d.z + d.w;
        }
    }
    dst[g0] = acc;
}

// ---------------------------------------------------------------------------
// prep: h[b, pos, :] -> A_hi/A_lo in MFMA fragment order (verified layout):
// idx = ((r16*(H/32) + kc)*64 + lh*16 + ll)*8 + j ; row = r16*16+ll,
// k = kc*32 + lh*8 + j.
// ---------------------------------------------------------------------------
__global__ __launch_bounds__(256) void prep_h(
    const float* __restrict__ hs, const int* __restrict__ pos_p,
    unsigned short* __restrict__ Ahi, unsigned short* __restrict__ Alo,
    int H, int L)
{
    const int pos = pos_p[0];
    const int tid = blockIdx.x * 256 + threadIdx.x;   // B*H/16 threads
    const int b     = tid >> 8;                       // 0..63
    const int kbase = (tid & 255) * 16;               // 0..4080
    const float* src = hs + ((size_t)b * L + pos) * H + kbase;
    float f[16];
    *(float4*)&f[0]  = *(const float4*)(src);
    *(float4*)&f[4]  = *(const float4*)(src + 4);
    *(float4*)&f[8]  = *(const float4*)(src + 8);
    *(float4*)&f[12] = *(const float4*)(src + 12);

    const int r16 = b >> 4, ll = b & 15;
    const int kc  = kbase >> 5;
    const int lh0 = (kbase >> 3) & 3;
#pragma unroll
    for (int c = 0; c < 2; ++c) {
        uint4 hi, lo;
        split8(f + 8 * c, hi, lo);
        const size_t dst = ((size_t)(r16 * (H >> 5) + kc) * 64 + (lh0 + c) * 16 + ll) * 8;
        *(uint4*)&Ahi[dst] = hi;
        *(uint4*)&Alo[dst] = lo;
    }
}

// ---------------------------------------------------------------------------
// GEMM: identical to round 8 (verified, absmax 0).
// ---------------------------------------------------------------------------
#define NWF    512               // floats per window per row
#define WTILES 16                // 32-k MFMA tiles per window

__global__ __launch_bounds__(256, 2) void logits_mfma(
    const float* __restrict__ emb,              // [V][H] fp32
    const unsigned short* __restrict__ Ahi,     // frag-ordered bf16
    const unsigned short* __restrict__ Alo,
    const float* __restrict__ temps,            // [B]
    const float* __restrict__ bias,             // [V]
    float*       __restrict__ out,              // [B][V] scaled logits
    int V, int H)
{
    __shared__ float sB[2][16 * NWF];           // 2 x 32 KB

    const int tid  = threadIdx.x;
    const int lane = tid & 63;
    const int w    = tid >> 6;
    const int v0   = blockIdx.x * 16;

    const int ll = lane & 15;                   // frag col (vocab row idx)
    const int lh = lane >> 4;                   // k sub-chunk

    const int NWIN = H / NWF;                   // 8 (power of 2)
    const int wst  = (blockIdx.x & 3) * 2;      // rotation start window

    // A fragment base: r16-block = w (wave's batch 16-block)
    const size_t aoff = (size_t)w * ((size_t)H * 16)
                      + (size_t)lh * 128 + (size_t)ll * 8;

    bf16x8 aih[2], ail[2];                      // A frags, parity buffer
    f32x4  acc = (f32x4){0.f, 0.f, 0.f, 0.f};

#define STAGE(win, bf) do {                                                   \
    _Pragma("unroll")                                                         \
    for (int rr = 0; rr < 4; ++rr) {                                          \
        const int r = w * 4 + rr;                                             \
        int rg = v0 + r;                                                      \
        rg = (rg < V) ? rg : (V - 1);                                         \
        const float* rowp = emb + (size_t)rg * H + (size_t)(win) * NWF        \
                          + ((lane * 4) ^ ((r & 15) << 2));                   \
        _Pragma("unroll")                                                     \
        for (int c = 0; c < 2; ++c) {                                         \
            __builtin_amdgcn_global_load_lds(                                 \
                (const __attribute__((address_space(1))) void*)(rowp + c * 256), \
                (__attribute__((address_space(3))) void*)&sB[bf][r * NWF + c * 256], \
                16, 0, 0);                                                    \
        }                                                                     \
    }                                                                         \
} while (0)

#define LOADA(T, p) do {                                                      \
    const size_t ai = aoff + (size_t)(T) * 512;                               \
    aih[p] = *(const bf16x8*)&Ahi[ai];                                        \
    ail[p] = *(const bf16x8*)&Alo[ai];                                        \
} while (0)

    // prologue
    LOADA(wst * WTILES, 0);
    STAGE(wst, 0);
    __syncthreads();

    for (int ws = 0; ws < NWIN; ++ws) {
        const int bf = ws & 1;
        if (ws + 1 < NWIN) STAGE((wst + ws + 1) & (NWIN - 1), bf ^ 1);

#pragma unroll
        for (int kt = 0; kt < WTILES; ++kt) {
            const int p = kt & 1;
            if (!(ws == NWIN - 1 && kt == WTILES - 1)) {
                const int wsn = ws + ((kt + 1) >> 4);
                const int ktn = (kt + 1) & 15;
                const int T1  = (((wst + wsn) & (NWIN - 1)) << 4) + ktn;
                LOADA(T1, p ^ 1);
            }

            const int f0   = kt * 32 + lh * 8;
            const int sidx = ll << 2;
            float f[8];
            *(float4*)&f[0] = *(const float4*)&sB[bf][ll * NWF + ((f0)     ^ sidx)];
            *(float4*)&f[4] = *(const float4*)&sB[bf][ll * NWF + ((f0 + 4) ^ sidx)];
            bf16x8 fbh, fbl;
            split8v(f, fbh, fbl);

            acc = __builtin_amdgcn_mfma_f32_16x16x32_bf16(ail[p], fbh, acc, 0, 0, 0);
            acc = __builtin_amdgcn_mfma_f32_16x16x32_bf16(aih[p], fbl, acc, 0, 0, 0);
            acc = __builtin_amdgcn_mfma_f32_16x16x32_bf16(aih[p], fbh, acc, 0, 0, 0);
        }
        __syncthreads();
    }
#undef STAGE
#undef LOADA

    // epilogue: C col = ll (vocab), row = lh*4 + r (batch within wave block)
    const int vv = v0 + ll;
    if (vv < V) {
        const float bv = bias[vv];
#pragma unroll
        for (int r = 0; r < 4; ++r) {
            const int b = w * 16 + lh * 4 + r;
            out[(size_t)b * V + vv] = (acc[r] + bv) / temps[b];
        }
    }
}

// ---------------------------------------------------------------------------
// JAX threefry2x32 gumbel — partitionable path (verified round 2).
// ---------------------------------------------------------------------------
__device__ __forceinline__ uint32_t rotl32(uint32_t x, int d) {
    return (x << d) | (x >> (32 - d));
}

__device__ float jax_gumbel(uint32_t flat) {
    const uint32_t k0 = 0u, k1 = 42u;
    const uint32_t ks[3] = { k0, k1, k0 ^ k1 ^ 0x1BD11BDAu };
    uint32_t x0 = 0u   + ks[0];
    uint32_t x1 = flat + ks[1];
    const int rot[2][4] = { {13, 15, 26, 6}, {17, 29, 16, 24} };
#pragma unroll
    for (int r = 0; r < 5; ++r) {
        const int* rr = rot[r & 1];
#pragma unroll
        for (int j = 0; j < 4; ++j) {
            x0 += x1;
            x1 = rotl32(x1, rr[j]);
            x1 ^= x0;
        }
        x0 += ks[(r + 1) % 3];
        x1 += ks[(r + 2) % 3] + (uint32_t)(r + 1);
    }
    const uint32_t bits = x0 ^ x1;
    const uint32_t fb = (bits >> 9) | 0x3F800000u;
    const float f = __uint_as_float(fb) - 1.0f;
    const float tiny = 1.17549435e-38f;
    float u = __fadd_rn(__fmul_rn(f, 1.0f), tiny);
    u = fmaxf(tiny, u);
    const float l1 = logf(u);
    return -logf(-l1);
}

// ---------------------------------------------------------------------------
// Per-batch sampling: one block per row. (unchanged, verified round 2)
// ---------------------------------------------------------------------------
#define NBINS 4096
#define CAP   2048
#define NKEEP 64

__global__ __launch_bounds__(256) void sample_kernel(
    const float* __restrict__ logits,  // [B][V] scaled
    const float* __restrict__ top_ps,  // [B]
    const int*   __restrict__ top_ks,  // [B]
    int*         __restrict__ out_ids, // [B]
    int V)
{
    const int b = blockIdx.x;
    const int tid = threadIdx.x;
    const float* row = logits + (size_t)b * V;

    __shared__ float swred[4];
    __shared__ int   bins[NBINS];
    __shared__ int   schunk[256];
    __shared__ int   sThrBin, sCnt, sMkeep;
    __shared__ float cval[CAP];
    __shared__ int   cidx[CAP];
    __shared__ float tval[NKEEP];
    __shared__ int   tidxs[NKEEP];

    // ---- pass 1: row max ----
    float m = -INFINITY;
    for (int k = tid; k < V; k += 256) m = fmaxf(m, row[k]);
#pragma unroll
    for (int o = 32; o > 0; o >>= 1) m = fmaxf(m, __shfl_xor(m, o, 64));
    if ((tid & 63) == 0) swred[tid >> 6] = m;
    __syncthreads();
    m = fmaxf(fmaxf(swred[0], swred[1]), fmaxf(swred[2], swred[3]));

    // ---- zero histogram ----
    for (int k = tid; k < NBINS; k += 256) bins[k] = 0;
    if (tid == 0) sCnt = 0;
    __syncthreads();

    // ---- pass 2: sum(exp(x-m)) + histogram of g = m - x ----
    float s = 0.f;
    for (int k = tid; k < V; k += 256) {
        const float x = row[k];
        s += expf(x - m);
        const float g = m - x;
        int bin = (int)(g * 256.0f);
        if (bin >= NBINS) bin = NBINS - 1;
        atomicAdd(&bins[bin], 1);
    }
#pragma unroll
    for (int o = 32; o > 0; o >>= 1) s += __shfl_xor(s, o, 64);
    __syncthreads();
    if ((tid & 63) == 0) swred[tid >> 6] = s;

    int csum = 0;
#pragma unroll
    for (int k = 0; k < NBINS / 256; ++k) csum += bins[tid * (NBINS / 256) + k];
    schunk[tid] = csum;
    __syncthreads();
    s = swred[0] + swred[1] + swred[2] + swred[3];
    if (tid == 0) {
        int cum = 0, chunk = 255;
        for (int c = 0; c < 256; ++c) {
            if (cum + schunk[c] >= NKEEP) { chunk = c; break; }
            cum += schunk[c];
        }
        int t = NBINS - 1;
        const int base = chunk * (NBINS / 256);
        for (int k = base; k < base + NBINS / 256; ++k) {
            cum += bins[k];
            if (cum >= NKEEP) { t = k; break; }
        }
        sThrBin = t;
    }
    __syncthreads();
    const int thrBin = sThrBin;

    // ---- pass 3: compact candidates ----
    for (int k = tid; k < V; k += 256) {
        const float x = row[k];
        const float g = m - x;
        int bin = (int)(g * 256.0f);
        if (bin >= NBINS) bin = NBINS - 1;
        if (bin <= thrBin) {
            const int p = atomicAdd(&sCnt, 1);
            if (p < CAP) { cval[p] = x; cidx[p] = k; }
        }
    }
    __syncthreads();
    const int C = min(sCnt, CAP);

    // ---- pass 4: rank-select top NKEEP ----
    for (int i = tid; i < C; i += 256) {
        const float vi = cval[i];
        const int   ii = cidx[i];
        int rank = 0;
        for (int j = 0; j < C; ++j) {
            const float vj = cval[j];
            const int   ij = cidx[j];
            rank += (vj > vi) || (vj == vi && ij < ii);
        }
        if (rank < NKEEP) { tval[rank] = vi; tidxs[rank] = ii; }
    }
    __syncthreads();

    // ---- pass 5: serial top-p/top-k cut ----
    if (tid == 0) {
        const float pb = top_ps[b];
        const int   kk = top_ks[b];
        const int   nk = min(NKEEP, C);
        float cum = 0.f;
        int mk = 0;
        for (int r = 0; r < nk; ++r) {
            const float pr = expf(tval[r] - m) / s;
            cum += pr;
            const float excl = cum - pr;
            if (excl > pb || r >= kk) break;
            ++mk;
        }
        sMkeep = (mk > 0) ? mk : 1;
    }
    __syncthreads();
    const int mkeep = sMkeep;

    // ---- pass 6: gumbel argmax over kept prefix ----
    if (tid < 64) {
        float sc = -INFINITY;
        int vid = INT_MAX;
        if (tid < mkeep) {
            const int v = tidxs[tid];
            vid = v;
            sc = tval[tid] + jax_gumbel((uint32_t)b * (uint32_t)V + (uint32_t)v);
        }
#pragma unroll
        for (int o = 32; o > 0; o >>= 1) {
            const float os = __shfl_xor(sc, o, 64);
            const int   ov = __shfl_xor(vid, o, 64);
            if (os > sc || (os == sc && ov < vid)) { sc = os; vid = ov; }
        }
        if (tid == 0) out_ids[b] = vid;
    }
}

extern "C" void kernel_launch(void* const* d_in, const int* in_sizes, int n_in,
                              void* d_out, int out_size, void* d_ws, size_t ws_size,
                              hipStream_t stream)
{
    const float* emb   = (const float*)d_in[0];
    const float* hs    = (const float*)d_in[1];
    const int*   pos   = (const int*)d_in[2];
    const float* temps = (const float*)d_in[3];
    const float* tps   = (const float*)d_in[4];
    const int*   tks   = (const int*)d_in[5];
    const float* bias  = (const float*)d_in[6];

    const int B = in_sizes[3];                     // temperatures
    const int V = in_sizes[6];                     // bias
    const int H = (int)((long long)in_sizes[0] / V);
    const int L = (int)((long long)in_sizes[1] / ((long long)B * H));

    float*          logits = (float*)d_ws;                        // B*V fp32
    unsigned short* Ahi    = (unsigned short*)((char*)d_ws + (16u << 20));
    unsigned short* Alo    = Ahi + (size_t)B * H;                 // 512 KB each
    float*          probeo = (float*)((char*)d_ws + (48u << 20)); // 2 MB

    // --- measurement dispatch: ideal-pattern streaming read, 2x emb ---
    const long n4 = ((long)in_sizes[0]) / 4;       // emb float4 count
    read_probe<<<2048, 256, 0, stream>>>((const float4*)emb, probeo, n4);

    prep_h<<<(B * H) / (16 * 256), 256, 0, stream>>>(hs, pos, Ahi, Alo, H, L);

    const int nblk = (V + 15) / 16;
    logits_mfma<<<nblk, 256, 0, stream>>>(emb, Ahi, Alo, temps, bias,
                                          logits, V, H);

    sample_kernel<<<B, 256, 0, stream>>>(logits, tps, tks, (int*)d_out, V);
}

// Round 10
// 390.359 us; speedup vs baseline: 1.7478x; 1.7478x over previous
//
#include <hip/hip_runtime.h>
#include <stdint.h>
#include <float.h>
#include <limits.h>

// ---------------------------------------------------------------------------
// Sampler: logits = (h @ E^T + bias) / T; softmax; top-p/top-k mask;
// jax.random.categorical(key(42)) == argmax(logp + gumbel) over kept set.
// GEMM via bf16 MFMA, 3-term split (loA*hiB + hiA*loB + hiA*hiB), k-ascending.
// Round 10: counted-vmcnt deep pipeline (T3/T4). Probe (r9) proved the read
// ceiling is ~5.5 TB/s; all prior GEMMs drained vmcnt to 0 at every barrier
// (sawtooth outstanding -> ~2.6 TB/s). Now: ring-4 LDS windows (1 KB/row
// global_load_lds bursts), raw s_barrier + asm "s_waitcnt vmcnt(24)" keeping
// 2 B-windows in flight at all times; A-frags in dual-bank VGPRs issued
// BEFORE the B-stages (FIFO: waiting for A never drains younger B).
// ---------------------------------------------------------------------------

typedef __bf16 bf16x8 __attribute__((ext_vector_type(8)));
typedef float  f32x4  __attribute__((ext_vector_type(4)));

__device__ __forceinline__ void split8v(const float* f, bf16x8& hi, bf16x8& lo) {
#pragma unroll
    for (int e = 0; e < 8; ++e) {
        const __bf16 h = (__bf16)f[e];
        hi[e] = h;
        lo[e] = (__bf16)(f[e] - (float)h);
    }
}
__device__ __forceinline__ void split8(const float* f, uint4& hi, uint4& lo) {
    bf16x8 vh, vl;
    split8v(f, vh, vl);
    hi = __builtin_bit_cast(uint4, vh);
    lo = __builtin_bit_cast(uint4, vl);
}

// ---------------------------------------------------------------------------
// prep: h[b, pos, :] -> A_hi/A_lo in MFMA fragment order (verified layout):
// idx = ((r16*(H/32) + kc)*64 + lh*16 + ll)*8 + j ; row = r16*16+ll,
// k = kc*32 + lh*8 + j.
// ---------------------------------------------------------------------------
__global__ __launch_bounds__(256) void prep_h(
    const float* __restrict__ hs, const int* __restrict__ pos_p,
    unsigned short* __restrict__ Ahi, unsigned short* __restrict__ Alo,
    int H, int L)
{
    const int pos = pos_p[0];
    const int tid = blockIdx.x * 256 + threadIdx.x;   // B*H/16 threads
    const int b     = tid >> 8;                       // 0..63
    const int kbase = (tid & 255) * 16;               // 0..4080
    const float* src = hs + ((size_t)b * L + pos) * H + kbase;
    float f[16];
    *(float4*)&f[0]  = *(const float4*)(src);
    *(float4*)&f[4]  = *(const float4*)(src + 4);
    *(float4*)&f[8]  = *(const float4*)(src + 8);
    *(float4*)&f[12] = *(const float4*)(src + 12);

    const int r16 = b >> 4, ll = b & 15;
    const int kc  = kbase >> 5;
    const int lh0 = (kbase >> 3) & 3;
#pragma unroll
    for (int c = 0; c < 2; ++c) {
        uint4 hi, lo;
        split8(f + 8 * c, hi, lo);
        const size_t dst = ((size_t)(r16 * (H >> 5) + kc) * 64 + (lh0 + c) * 16 + ll) * 8;
        *(uint4*)&Ahi[dst] = hi;
        *(uint4*)&Alo[dst] = lo;
    }
}

// ---------------------------------------------------------------------------
// GEMM: grid ceil(V/16) x 256 thr. Block = 16 contiguous vocab rows x all 64
// batch; wave w = batch 16-block w. B staged in 256-float windows (1 KB/row
// global_load_lds), ring-4 LDS, counted vmcnt (never 0 in loop), raw barrier.
// ---------------------------------------------------------------------------
#define NWF 256                  // floats per window per row
#define RING 4

__global__ __launch_bounds__(256, 2) void logits_mfma(
    const float* __restrict__ emb,              // [V][H] fp32
    const unsigned short* __restrict__ Ahi,     // frag-ordered bf16
    const unsigned short* __restrict__ Alo,
    const float* __restrict__ temps,            // [B]
    const float* __restrict__ bias,             // [V]
    float*       __restrict__ out,              // [B][V] scaled logits
    int V, int H)
{
    __shared__ float sB[RING][16 * NWF];        // 4 x 16 KB = 64 KB

    const int tid  = threadIdx.x;
    const int lane = tid & 63;
    const int w    = tid >> 6;
    const int v0   = blockIdx.x * 16;

    const int ll  = lane & 15;                  // frag col (vocab row idx)
    const int lh  = lane >> 4;                  // k sub-chunk
    const int swz = ll << 2;                    // read-side XOR (matches store)

    const int NW = H / NWF;                     // 16 windows

    // A fragment base: r16-block = w
    const size_t aoff = (size_t)w * ((size_t)H * 16)
                      + (size_t)lh * 128 + (size_t)ll * 8;

    bf16x8 Ah0[8], Al0[8], Ah1[8], Al1[8];      // dual-bank A window frags
    f32x4  acc = (f32x4){0.f, 0.f, 0.f, 0.f};

    // 16 x 16B loads per window into a named bank (compile-time regs)
#define LOADA(win, AH, AL) do {                                               \
    _Pragma("unroll")                                                         \
    for (int kt = 0; kt < 8; ++kt) {                                          \
        const size_t ai = aoff + ((size_t)(win) * 8 + kt) * 512;              \
        AH[kt] = *(const bf16x8*)&Ahi[ai];                                    \
        AL[kt] = *(const bf16x8*)&Alo[ai];                                    \
    }                                                                         \
} while (0)

    // 4 x global_load_lds (1 KB contiguous from one row each); source
    // pre-XOR-swizzled, linear LDS dest (rule #21)
#define STAGE(win, slot) do {                                                 \
    _Pragma("unroll")                                                         \
    for (int rr = 0; rr < 4; ++rr) {                                          \
        const int r = w * 4 + rr;                                             \
        int rg = v0 + r;                                                      \
        rg = (rg < V) ? rg : (V - 1);                                         \
        const float* srcp = emb + (size_t)rg * H + (size_t)(win) * NWF        \
                          + ((lane * 4) ^ ((r & 15) << 2));                   \
        __builtin_amdgcn_global_load_lds(                                     \
            (const __attribute__((address_space(1))) void*)srcp,              \
            (__attribute__((address_space(3))) void*)&sB[slot][r * NWF],      \
            16, 0, 0);                                                        \
    }                                                                         \
} while (0)

#define COMPUTE(AH, AL, slot) do {                                            \
    _Pragma("unroll")                                                         \
    for (int kt = 0; kt < 8; ++kt) {                                          \
        const int f0 = kt * 32 + lh * 8;                                      \
        float f[8];                                                           \
        *(float4*)&f[0] = *(const float4*)&sB[slot][ll * NWF + ((f0)     ^ swz)]; \
        *(float4*)&f[4] = *(const float4*)&sB[slot][ll * NWF + ((f0 + 4) ^ swz)]; \
        bf16x8 fbh, fbl;                                                      \
        split8v(f, fbh, fbl);                                                 \
        acc = __builtin_amdgcn_mfma_f32_16x16x32_bf16(AL[kt], fbh, acc, 0, 0, 0); \
        acc = __builtin_amdgcn_mfma_f32_16x16x32_bf16(AH[kt], fbl, acc, 0, 0, 0); \
        acc = __builtin_amdgcn_mfma_f32_16x16x32_bf16(AH[kt], fbh, acc, 0, 0, 0); \
    }                                                                         \
} while (0)

#define SB __builtin_amdgcn_sched_barrier(0)

    // prologue: A(0)->bank0, stage windows 0,1   (pending: A0=16, S0=4, S1=4)
    LOADA(0, Ah0, Al0);
    SB;
    STAGE(0, 0);
    STAGE(1, 1);
    SB;

    // steady loop: windows 0..NW-3, unrolled x2 for compile-time A banks.
    // per window: issue A(w+1), S(w+2); wait vmcnt(24) == retire {S(w), A(w)},
    // keep {S(w+1), A(w+1), S(w+2)} in flight; barrier; compute.
    for (int m = 0; m < NW / 2 - 1; ++m) {
        const int w0 = 2 * m;
        LOADA(w0 + 1, Ah1, Al1);
        SB;
        STAGE(w0 + 2, ((w0 + 2) & (RING - 1)));
        SB;
        asm volatile("s_waitcnt vmcnt(24)" ::: "memory");
        __builtin_amdgcn_s_barrier();
        COMPUTE(Ah0, Al0, (w0 & (RING - 1)));

        LOADA(w0 + 2, Ah0, Al0);
        SB;
        STAGE(w0 + 3, ((w0 + 3) & (RING - 1)));
        SB;
        asm volatile("s_waitcnt vmcnt(24)" ::: "memory");
        __builtin_amdgcn_s_barrier();
        COMPUTE(Ah1, Al1, ((w0 + 1) & (RING - 1)));
    }
    // peel w = NW-2 (even -> bank0 holds A(NW-2))
    LOADA(NW - 1, Ah1, Al1);
    SB;
    asm volatile("s_waitcnt vmcnt(20)" ::: "memory");
    __builtin_amdgcn_s_barrier();
    COMPUTE(Ah0, Al0, ((NW - 2) & (RING - 1)));
    // peel w = NW-1
    asm volatile("s_waitcnt vmcnt(0)" ::: "memory");
    __builtin_amdgcn_s_barrier();
    COMPUTE(Ah1, Al1, ((NW - 1) & (RING - 1)));

#undef LOADA
#undef STAGE
#undef COMPUTE
#undef SB

    // epilogue: C col = ll (vocab), row = lh*4 + r (batch within wave block)
    const int vv = v0 + ll;
    if (vv < V) {
        const float bv = bias[vv];
#pragma unroll
        for (int r = 0; r < 4; ++r) {
            const int b = w * 16 + lh * 4 + r;
            out[(size_t)b * V + vv] = (acc[r] + bv) / temps[b];
        }
    }
}

// ---------------------------------------------------------------------------
// JAX threefry2x32 gumbel — partitionable path (verified round 2).
// ---------------------------------------------------------------------------
__device__ __forceinline__ uint32_t rotl32(uint32_t x, int d) {
    return (x << d) | (x >> (32 - d));
}

__device__ float jax_gumbel(uint32_t flat) {
    const uint32_t k0 = 0u, k1 = 42u;
    const uint32_t ks[3] = { k0, k1, k0 ^ k1 ^ 0x1BD11BDAu };
    uint32_t x0 = 0u   + ks[0];
    uint32_t x1 = flat + ks[1];
    const int rot[2][4] = { {13, 15, 26, 6}, {17, 29, 16, 24} };
#pragma unroll
    for (int r = 0; r < 5; ++r) {
        const int* rr = rot[r & 1];
#pragma unroll
        for (int j = 0; j < 4; ++j) {
            x0 += x1;
            x1 = rotl32(x1, rr[j]);
            x1 ^= x0;
        }
        x0 += ks[(r + 1) % 3];
        x1 += ks[(r + 2) % 3] + (uint32_t)(r + 1);
    }
    const uint32_t bits = x0 ^ x1;
    const uint32_t fb = (bits >> 9) | 0x3F800000u;
    const float f = __uint_as_float(fb) - 1.0f;
    const float tiny = 1.17549435e-38f;
    float u = __fadd_rn(__fmul_rn(f, 1.0f), tiny);
    u = fmaxf(tiny, u);
    const float l1 = logf(u);
    return -logf(-l1);
}

// ---------------------------------------------------------------------------
// Per-batch sampling: one block per row. (unchanged, verified round 2)
// ---------------------------------------------------------------------------
#define NBINS 4096
#define CAP   2048
#define NKEEP 64

__global__ __launch_bounds__(256) void sample_kernel(
    const float* __restrict__ logits,  // [B][V] scaled
    const float* __restrict__ top_ps,  // [B]
    const int*   __restrict__ top_ks,  // [B]
    int*         __restrict__ out_ids, // [B]
    int V)
{
    const int b = blockIdx.x;
    const int tid = threadIdx.x;
    const float* row = logits + (size_t)b * V;

    __shared__ float swred[4];
    __shared__ int   bins[NBINS];
    __shared__ int   schunk[256];
    __shared__ int   sThrBin, sCnt, sMkeep;
    __shared__ float cval[CAP];
    __shared__ int   cidx[CAP];
    __shared__ float tval[NKEEP];
    __shared__ int   tidxs[NKEEP];

    // ---- pass 1: row max ----
    float m = -INFINITY;
    for (int k = tid; k < V; k += 256) m = fmaxf(m, row[k]);
#pragma unroll
    for (int o = 32; o > 0; o >>= 1) m = fmaxf(m, __shfl_xor(m, o, 64));
    if ((tid & 63) == 0) swred[tid >> 6] = m;
    __syncthreads();
    m = fmaxf(fmaxf(swred[0], swred[1]), fmaxf(swred[2], swred[3]));

    // ---- zero histogram ----
    for (int k = tid; k < NBINS; k += 256) bins[k] = 0;
    if (tid == 0) sCnt = 0;
    __syncthreads();

    // ---- pass 2: sum(exp(x-m)) + histogram of g = m - x ----
    float s = 0.f;
    for (int k = tid; k < V; k += 256) {
        const float x = row[k];
        s += expf(x - m);
        const float g = m - x;
        int bin = (int)(g * 256.0f);
        if (bin >= NBINS) bin = NBINS - 1;
        atomicAdd(&bins[bin], 1);
    }
#pragma unroll
    for (int o = 32; o > 0; o >>= 1) s += __shfl_xor(s, o, 64);
    __syncthreads();
    if ((tid & 63) == 0) swred[tid >> 6] = s;

    int csum = 0;
#pragma unroll
    for (int k = 0; k < NBINS / 256; ++k) csum += bins[tid * (NBINS / 256) + k];
    schunk[tid] = csum;
    __syncthreads();
    s = swred[0] + swred[1] + swred[2] + swred[3];
    if (tid == 0) {
        int cum = 0, chunk = 255;
        for (int c = 0; c < 256; ++c) {
            if (cum + schunk[c] >= NKEEP) { chunk = c; break; }
            cum += schunk[c];
        }
        int t = NBINS - 1;
        const int base = chunk * (NBINS / 256);
        for (int k = base; k < base + NBINS / 256; ++k) {
            cum += bins[k];
            if (cum >= NKEEP) { t = k; break; }
        }
        sThrBin = t;
    }
    __syncthreads();
    const int thrBin = sThrBin;

    // ---- pass 3: compact candidates ----
    for (int k = tid; k < V; k += 256) {
        const float x = row[k];
        const float g = m - x;
        int bin = (int)(g * 256.0f);
        if (bin >= NBINS) bin = NBINS - 1;
        if (bin <= thrBin) {
            const int p = atomicAdd(&sCnt, 1);
            if (p < CAP) { cval[p] = x; cidx[p] = k; }
        }
    }
    __syncthreads();
    const int C = min(sCnt, CAP);

    // ---- pass 4: rank-select top NKEEP ----
    for (int i = tid; i < C; i += 256) {
        const float vi = cval[i];
        const int   ii = cidx[i];
        int rank = 0;
        for (int j = 0; j < C; ++j) {
            const float vj = cval[j];
            const int   ij = cidx[j];
            rank += (vj > vi) || (vj == vi && ij < ii);
        }
        if (rank < NKEEP) { tval[rank] = vi; tidxs[rank] = ii; }
    }
    __syncthreads();

    // ---- pass 5: serial top-p/top-k cut ----
    if (tid == 0) {
        const float pb = top_ps[b];
        const int   kk = top_ks[b];
        const int   nk = min(NKEEP, C);
        float cum = 0.f;
        int mk = 0;
        for (int r = 0; r < nk; ++r) {
            const float pr = expf(tval[r] - m) / s;
            cum += pr;
            const float excl = cum - pr;
            if (excl > pb || r >= kk) break;
            ++mk;
        }
        sMkeep = (mk > 0) ? mk : 1;
    }
    __syncthreads();
    const int mkeep = sMkeep;

    // ---- pass 6: gumbel argmax over kept prefix ----
    if (tid < 64) {
        float sc = -INFINITY;
        int vid = INT_MAX;
        if (tid < mkeep) {
            const int v = tidxs[tid];
            vid = v;
            sc = tval[tid] + jax_gumbel((uint32_t)b * (uint32_t)V + (uint32_t)v);
        }
#pragma unroll
        for (int o = 32; o > 0; o >>= 1) {
            const float os = __shfl_xor(sc, o, 64);
            const int   ov = __shfl_xor(vid, o, 64);
            if (os > sc || (os == sc && ov < vid)) { sc = os; vid = ov; }
        }
        if (tid == 0) out_ids[b] = vid;
    }
}

extern "C" void kernel_launch(void* const* d_in, const int* in_sizes, int n_in,
                              void* d_out, int out_size, void* d_ws, size_t ws_size,
                              hipStream_t stream)
{
    const float* emb   = (const float*)d_in[0];
    const float* hs    = (const float*)d_in[1];
    const int*   pos   = (const int*)d_in[2];
    const float* temps = (const float*)d_in[3];
    const float* tps   = (const float*)d_in[4];
    const int*   tks   = (const int*)d_in[5];
    const float* bias  = (const float*)d_in[6];

    const int B = in_sizes[3];                     // temperatures
    const int V = in_sizes[6];                     // bias
    const int H = (int)((long long)in_sizes[0] / V);
    const int L = (int)((long long)in_sizes[1] / ((long long)B * H));

    float*          logits = (float*)d_ws;                        // B*V fp32
    unsigned short* Ahi    = (unsigned short*)((char*)d_ws + (16u << 20));
    unsigned short* Alo    = Ahi + (size_t)B * H;                 // 512 KB each

    prep_h<<<(B * H) / (16 * 256), 256, 0, stream>>>(hs, pos, Ahi, Alo, H, L);

    const int nblk = (V + 15) / 16;
    logits_mfma<<<nblk, 256, 0, stream>>>(emb, Ahi, Alo, temps, bias,
                                          logits, V, H);

    sample_kernel<<<B, 256, 0, stream>>>(logits, tps, tks, (int*)d_out, V);
}

// Round 11
// 370.360 us; speedup vs baseline: 1.8422x; 1.0540x over previous
//
#include <hip/hip_runtime.h>
#include <stdint.h>
#include <float.h>
#include <limits.h>

// ---------------------------------------------------------------------------
// Sampler: logits = (h @ E^T + bias) / T; softmax; top-p/top-k mask;
// jax.random.categorical(key(42)) == argmax(logp + gumbel) over kept set.
// GEMM via bf16 MFMA, 3-term split (loA*hiB + hiA*loB + hiA*hiB), k-ascending.
// Round 11: OCCUPANCY. r9 probe: 5.5 TB/s read at 32 waves/CU; all GEMMs so
// far: 2.6 TB/s at 8-12 waves/CU. Read BW scales with resident waves. Lean
// kernel: 32 KB LDS dbuf, no A-reg banks (per-tile L2 loads, compile-time
// indices), launch_bounds(256,5) -> ~20 waves/CU. One barrier per window.
// ---------------------------------------------------------------------------

typedef __bf16 bf16x8 __attribute__((ext_vector_type(8)));
typedef float  f32x4  __attribute__((ext_vector_type(4)));

__device__ __forceinline__ void split8v(const float* f, bf16x8& hi, bf16x8& lo) {
#pragma unroll
    for (int e = 0; e < 8; ++e) {
        const __bf16 h = (__bf16)f[e];
        hi[e] = h;
        lo[e] = (__bf16)(f[e] - (float)h);
    }
}
__device__ __forceinline__ void split8(const float* f, uint4& hi, uint4& lo) {
    bf16x8 vh, vl;
    split8v(f, vh, vl);
    hi = __builtin_bit_cast(uint4, vh);
    lo = __builtin_bit_cast(uint4, vl);
}

// ---------------------------------------------------------------------------
// prep: h[b, pos, :] -> A_hi/A_lo in MFMA fragment order (verified layout):
// idx = ((r16*(H/32) + kc)*64 + lh*16 + ll)*8 + j ; row = r16*16+ll,
// k = kc*32 + lh*8 + j.
// ---------------------------------------------------------------------------
__global__ __launch_bounds__(256) void prep_h(
    const float* __restrict__ hs, const int* __restrict__ pos_p,
    unsigned short* __restrict__ Ahi, unsigned short* __restrict__ Alo,
    int H, int L)
{
    const int pos = pos_p[0];
    const int tid = blockIdx.x * 256 + threadIdx.x;   // B*H/16 threads
    const int b     = tid >> 8;                       // 0..63
    const int kbase = (tid & 255) * 16;               // 0..4080
    const float* src = hs + ((size_t)b * L + pos) * H + kbase;
    float f[16];
    *(float4*)&f[0]  = *(const float4*)(src);
    *(float4*)&f[4]  = *(const float4*)(src + 4);
    *(float4*)&f[8]  = *(const float4*)(src + 8);
    *(float4*)&f[12] = *(const float4*)(src + 12);

    const int r16 = b >> 4, ll = b & 15;
    const int kc  = kbase >> 5;
    const int lh0 = (kbase >> 3) & 3;
#pragma unroll
    for (int c = 0; c < 2; ++c) {
        uint4 hi, lo;
        split8(f + 8 * c, hi, lo);
        const size_t dst = ((size_t)(r16 * (H >> 5) + kc) * 64 + (lh0 + c) * 16 + ll) * 8;
        *(uint4*)&Ahi[dst] = hi;
        *(uint4*)&Alo[dst] = lo;
    }
}

// ---------------------------------------------------------------------------
// GEMM: grid ceil(V/16) x 256 thr (4 waves). Block = 16 contiguous vocab rows
// x 64 batch; wave w = batch 16-block w. B staged in 256-float windows
// (1 KB/row global_load_lds), 2x16 KB dbuf, one __syncthreads per window.
// ---------------------------------------------------------------------------
#define NWF 256                  // floats per window per row

__global__ __launch_bounds__(256, 5) void logits_mfma(
    const float* __restrict__ emb,              // [V][H] fp32
    const unsigned short* __restrict__ Ahi,     // frag-ordered bf16
    const unsigned short* __restrict__ Alo,
    const float* __restrict__ temps,            // [B]
    const float* __restrict__ bias,             // [V]
    float*       __restrict__ out,              // [B][V] scaled logits
    int V, int H)
{
    __shared__ float sB[2][16 * NWF];           // 2 x 16 KB

    const int tid  = threadIdx.x;
    const int lane = tid & 63;
    const int w    = tid >> 6;
    const int v0   = blockIdx.x * 16;

    const int ll  = lane & 15;                  // frag col (vocab row idx)
    const int lh  = lane >> 4;                  // k sub-chunk
    const int swz = ll << 2;                    // read-side XOR (matches store)

    const int NW = H / NWF;                     // 16 windows

    // A fragment base: r16-block = w
    const unsigned short* pAh = Ahi + (size_t)w * ((size_t)H * 16)
                              + (size_t)lh * 128 + (size_t)ll * 8;
    const unsigned short* pAl = Alo + (size_t)w * ((size_t)H * 16)
                              + (size_t)lh * 128 + (size_t)ll * 8;

    f32x4 acc = (f32x4){0.f, 0.f, 0.f, 0.f};

    // 4 x global_load_lds (1 KB contiguous from one row each); source
    // pre-XOR-swizzled, linear LDS dest (rule #21; verified r8)
#define STAGE(win, slot) do {                                                 \
    _Pragma("unroll")                                                         \
    for (int rr = 0; rr < 4; ++rr) {                                          \
        const int r = w * 4 + rr;                                             \
        int rg = v0 + r;                                                      \
        rg = (rg < V) ? rg : (V - 1);                                         \
        const float* srcp = emb + (size_t)rg * H + (size_t)(win) * NWF        \
                          + ((lane * 4) ^ ((r & 15) << 2));                   \
        __builtin_amdgcn_global_load_lds(                                     \
            (const __attribute__((address_space(1))) void*)srcp,              \
            (__attribute__((address_space(3))) void*)&sB[slot][r * NWF],      \
            16, 0, 0);                                                        \
    }                                                                         \
} while (0)

    // prologue
    STAGE(0, 0);
    __syncthreads();

    for (int win = 0; win < NW; ++win) {
        const int bf = win & 1;
        if (win + 1 < NW) STAGE(win + 1, bf ^ 1);

        const size_t tbase = (size_t)win * 8;
#pragma unroll
        for (int kt = 0; kt < 8; ++kt) {
            // A frags for global tile (win*8 + kt), L2-resident
            const size_t ai = (tbase + kt) * 512;
            const bf16x8 ah = *(const bf16x8*)&pAh[ai];
            const bf16x8 al = *(const bf16x8*)&pAl[ai];

            // B frag from LDS (fp32, swizzled) -> split
            const int f0 = kt * 32 + lh * 8;
            float f[8];
            *(float4*)&f[0] = *(const float4*)&sB[bf][ll * NWF + ((f0)     ^ swz)];
            *(float4*)&f[4] = *(const float4*)&sB[bf][ll * NWF + ((f0 + 4) ^ swz)];
            bf16x8 fbh, fbl;
            split8v(f, fbh, fbl);

            acc = __builtin_amdgcn_mfma_f32_16x16x32_bf16(al, fbh, acc, 0, 0, 0);
            acc = __builtin_amdgcn_mfma_f32_16x16x32_bf16(ah, fbl, acc, 0, 0, 0);
            acc = __builtin_amdgcn_mfma_f32_16x16x32_bf16(ah, fbh, acc, 0, 0, 0);
        }
        __syncthreads();        // all waves done with sB[bf]; sB[bf^1] landed
    }
#undef STAGE

    // epilogue: C col = ll (vocab), row = lh*4 + r (batch within wave block)
    const int vv = v0 + ll;
    if (vv < V) {
        const float bv = bias[vv];
#pragma unroll
        for (int r = 0; r < 4; ++r) {
            const int b = w * 16 + lh * 4 + r;
            out[(size_t)b * V + vv] = (acc[r] + bv) / temps[b];
        }
    }
}

// ---------------------------------------------------------------------------
// JAX threefry2x32 gumbel — partitionable path (verified round 2).
// ---------------------------------------------------------------------------
__device__ __forceinline__ uint32_t rotl32(uint32_t x, int d) {
    return (x << d) | (x >> (32 - d));
}

__device__ float jax_gumbel(uint32_t flat) {
    const uint32_t k0 = 0u, k1 = 42u;
    const uint32_t ks[3] = { k0, k1, k0 ^ k1 ^ 0x1BD11BDAu };
    uint32_t x0 = 0u   + ks[0];
    uint32_t x1 = flat + ks[1];
    const int rot[2][4] = { {13, 15, 26, 6}, {17, 29, 16, 24} };
#pragma unroll
    for (int r = 0; r < 5; ++r) {
        const int* rr = rot[r & 1];
#pragma unroll
        for (int j = 0; j < 4; ++j) {
            x0 += x1;
            x1 = rotl32(x1, rr[j]);
            x1 ^= x0;
        }
        x0 += ks[(r + 1) % 3];
        x1 += ks[(r + 2) % 3] + (uint32_t)(r + 1);
    }
    const uint32_t bits = x0 ^ x1;
    const uint32_t fb = (bits >> 9) | 0x3F800000u;
    const float f = __uint_as_float(fb) - 1.0f;
    const float tiny = 1.17549435e-38f;
    float u = __fadd_rn(__fmul_rn(f, 1.0f), tiny);
    u = fmaxf(tiny, u);
    const float l1 = logf(u);
    return -logf(-l1);
}

// ---------------------------------------------------------------------------
// Per-batch sampling: one block per row. (unchanged, verified round 2)
// ---------------------------------------------------------------------------
#define NBINS 4096
#define CAP   2048
#define NKEEP 64

__global__ __launch_bounds__(256) void sample_kernel(
    const float* __restrict__ logits,  // [B][V] scaled
    const float* __restrict__ top_ps,  // [B]
    const int*   __restrict__ top_ks,  // [B]
    int*         __restrict__ out_ids, // [B]
    int V)
{
    const int b = blockIdx.x;
    const int tid = threadIdx.x;
    const float* row = logits + (size_t)b * V;

    __shared__ float swred[4];
    __shared__ int   bins[NBINS];
    __shared__ int   schunk[256];
    __shared__ int   sThrBin, sCnt, sMkeep;
    __shared__ float cval[CAP];
    __shared__ int   cidx[CAP];
    __shared__ float tval[NKEEP];
    __shared__ int   tidxs[NKEEP];

    // ---- pass 1: row max ----
    float m = -INFINITY;
    for (int k = tid; k < V; k += 256) m = fmaxf(m, row[k]);
#pragma unroll
    for (int o = 32; o > 0; o >>= 1) m = fmaxf(m, __shfl_xor(m, o, 64));
    if ((tid & 63) == 0) swred[tid >> 6] = m;
    __syncthreads();
    m = fmaxf(fmaxf(swred[0], swred[1]), fmaxf(swred[2], swred[3]));

    // ---- zero histogram ----
    for (int k = tid; k < NBINS; k += 256) bins[k] = 0;
    if (tid == 0) sCnt = 0;
    __syncthreads();

    // ---- pass 2: sum(exp(x-m)) + histogram of g = m - x ----
    float s = 0.f;
    for (int k = tid; k < V; k += 256) {
        const float x = row[k];
        s += expf(x - m);
        const float g = m - x;
        int bin = (int)(g * 256.0f);
        if (bin >= NBINS) bin = NBINS - 1;
        atomicAdd(&bins[bin], 1);
    }
#pragma unroll
    for (int o = 32; o > 0; o >>= 1) s += __shfl_xor(s, o, 64);
    __syncthreads();
    if ((tid & 63) == 0) swred[tid >> 6] = s;

    int csum = 0;
#pragma unroll
    for (int k = 0; k < NBINS / 256; ++k) csum += bins[tid * (NBINS / 256) + k];
    schunk[tid] = csum;
    __syncthreads();
    s = swred[0] + swred[1] + swred[2] + swred[3];
    if (tid == 0) {
        int cum = 0, chunk = 255;
        for (int c = 0; c < 256; ++c) {
            if (cum + schunk[c] >= NKEEP) { chunk = c; break; }
            cum += schunk[c];
        }
        int t = NBINS - 1;
        const int base = chunk * (NBINS / 256);
        for (int k = base; k < base + NBINS / 256; ++k) {
            cum += bins[k];
            if (cum >= NKEEP) { t = k; break; }
        }
        sThrBin = t;
    }
    __syncthreads();
    const int thrBin = sThrBin;

    // ---- pass 3: compact candidates ----
    for (int k = tid; k < V; k += 256) {
        const float x = row[k];
        const float g = m - x;
        int bin = (int)(g * 256.0f);
        if (bin >= NBINS) bin = NBINS - 1;
        if (bin <= thrBin) {
            const int p = atomicAdd(&sCnt, 1);
            if (p < CAP) { cval[p] = x; cidx[p] = k; }
        }
    }
    __syncthreads();
    const int C = min(sCnt, CAP);

    // ---- pass 4: rank-select top NKEEP ----
    for (int i = tid; i < C; i += 256) {
        const float vi = cval[i];
        const int   ii = cidx[i];
        int rank = 0;
        for (int j = 0; j < C; ++j) {
            const float vj = cval[j];
            const int   ij = cidx[j];
            rank += (vj > vi) || (vj == vi && ij < ii);
        }
        if (rank < NKEEP) { tval[rank] = vi; tidxs[rank] = ii; }
    }
    __syncthreads();

    // ---- pass 5: serial top-p/top-k cut ----
    if (tid == 0) {
        const float pb = top_ps[b];
        const int   kk = top_ks[b];
        const int   nk = min(NKEEP, C);
        float cum = 0.f;
        int mk = 0;
        for (int r = 0; r < nk; ++r) {
            const float pr = expf(tval[r] - m) / s;
            cum += pr;
            const float excl = cum - pr;
            if (excl > pb || r >= kk) break;
            ++mk;
        }
        sMkeep = (mk > 0) ? mk : 1;
    }
    __syncthreads();
    const int mkeep = sMkeep;

    // ---- pass 6: gumbel argmax over kept prefix ----
    if (tid < 64) {
        float sc = -INFINITY;
        int vid = INT_MAX;
        if (tid < mkeep) {
            const int v = tidxs[tid];
            vid = v;
            sc = tval[tid] + jax_gumbel((uint32_t)b * (uint32_t)V + (uint32_t)v);
        }
#pragma unroll
        for (int o = 32; o > 0; o >>= 1) {
            const float os = __shfl_xor(sc, o, 64);
            const int   ov = __shfl_xor(vid, o, 64);
            if (os > sc || (os == sc && ov < vid)) { sc = os; vid = ov; }
        }
        if (tid == 0) out_ids[b] = vid;
    }
}

extern "C" void kernel_launch(void* const* d_in, const int* in_sizes, int n_in,
                              void* d_out, int out_size, void* d_ws, size_t ws_size,
                              hipStream_t stream)
{
    const float* emb   = (const float*)d_in[0];
    const float* hs    = (const float*)d_in[1];
    const int*   pos   = (const int*)d_in[2];
    const float* temps = (const float*)d_in[3];
    const float* tps   = (const float*)d_in[4];
    const int*   tks   = (const int*)d_in[5];
    const float* bias  = (const float*)d_in[6];

    const int B = in_sizes[3];                     // temperatures
    const int V = in_sizes[6];                     // bias
    const int H = (int)((long long)in_sizes[0] / V);
    const int L = (int)((long long)in_sizes[1] / ((long long)B * H));

    float*          logits = (float*)d_ws;                        // B*V fp32
    unsigned short* Ahi    = (unsigned short*)((char*)d_ws + (16u << 20));
    unsigned short* Alo    = Ahi + (size_t)B * H;                 // 512 KB each

    prep_h<<<(B * H) / (16 * 256), 256, 0, stream>>>(hs, pos, Ahi, Alo, H, L);

    const int nblk = (V + 15) / 16;
    logits_mfma<<<nblk, 256, 0, stream>>>(emb, Ahi, Alo, temps, bias,
                                          logits, V, H);

    sample_kernel<<<B, 256, 0, stream>>>(logits, tps, tks, (int*)d_out, V);
}